// Round 18
// baseline (865.768 us; speedup 1.0000x reference)
//
#include <hip/hip_runtime.h>

typedef unsigned short u16;
typedef float f32x4 __attribute__((ext_vector_type(4)));
typedef short s16x8 __attribute__((ext_vector_type(8)));
typedef u16   u16x4 __attribute__((ext_vector_type(4)));

#define DEV static __device__ __forceinline__

DEV u16 f2b(float f){
  unsigned u = __builtin_bit_cast(unsigned, f);
  u += 0x7fffu + ((u >> 16) & 1u);
  return (u16)(u >> 16);
}
DEV float b2f(u16 h){ unsigned u = ((unsigned)h) << 16; return __builtin_bit_cast(float, u); }
// truncation split: hi = trunc-to-bf16(v); lo = trunc(v - hi). 2-term error ~2^-16 rel.
DEV void tsplit(float v, u16& hv, u16& lv){
  unsigned u = __builtin_bit_cast(unsigned, v);
  hv = (u16)(u >> 16);
  float rest = v - __builtin_bit_cast(float, u & 0xffff0000u);
  lv = (u16)(__builtin_bit_cast(unsigned, rest) >> 16);
}
DEV float fexp2(float x){ float r; asm("v_exp_f32 %0, %1" : "=v"(r) : "v"(x)); return r; }

// async global->LDS, 16B per lane. LDS dest wave-uniform base; HW adds lane*16.
DEV void glds16(const u16* g, u16* l){
  __builtin_amdgcn_global_load_lds(
      (const __attribute__((address_space(1))) void*)g,
      (__attribute__((address_space(3))) void*)l, 16, 0, 0);
}

DEV f32x4 mfma3(s16x8 ah, s16x8 al, s16x8 bh, s16x8 bl, f32x4 c){
  c = __builtin_amdgcn_mfma_f32_16x16x32_bf16(ah, bh, c, 0, 0, 0);
  c = __builtin_amdgcn_mfma_f32_16x16x32_bf16(ah, bl, c, 0, 0, 0);
  c = __builtin_amdgcn_mfma_f32_16x16x32_bf16(al, bh, c, 0, 0, 0);
  return c;
}

constexpr int TT = 1024, DM = 1024, NE = 8, FFD = 4096;
constexpr int NTOK = 4096;

// ---------------- transpose fp32 [1024][1024] -> bf16 hi/lo [C][R] ----------------
struct Ptr8 { const float* p[8]; };

__global__ __launch_bounds__(256) void trans8_k(Ptr8 srcs, u16* __restrict__ dh, u16* __restrict__ dl){
  __shared__ float tl[64][65];
  const float* src = srcs.p[blockIdx.z];
  u16* dsth = dh + (size_t)blockIdx.z * 1024 * 1024;
  u16* dstl = dl + (size_t)blockIdx.z * 1024 * 1024;
  const int tid = threadIdx.x;
  const int r0 = blockIdx.y * 64, c0 = blockIdx.x * 64;
  const int ty = tid >> 4, tx = tid & 15;
#pragma unroll
  for (int i = 0; i < 4; i++){
    int row = ty + i * 16;
    f32x4 v = *(const f32x4*)&src[(size_t)(r0 + row) * 1024 + c0 + tx * 4];
#pragma unroll
    for (int j = 0; j < 4; j++) tl[row][tx * 4 + j] = v[j];
  }
  __syncthreads();
#pragma unroll
  for (int i = 0; i < 4; i++){
    int drow = ty + i * 16;
    u16x4 oh, ol;
#pragma unroll
    for (int j = 0; j < 4; j++){
      float v = tl[tx * 4 + j][drow];
      u16 hh, ll; tsplit(v, hh, ll);
      oh[j] = hh; ol[j] = ll;
    }
    *(u16x4*)&dsth[(size_t)(c0 + drow) * 1024 + r0 + tx * 4] = oh;
    *(u16x4*)&dstl[(size_t)(c0 + drow) * 1024 + r0 + tx * 4] = ol;
  }
}

// single-bf16 transpose for MoE weights
__global__ __launch_bounds__(256) void transb_k(const float* __restrict__ src0, u16* __restrict__ dst0, int R, int C){
  __shared__ float tl[64][65];
  const float* src = src0 + (size_t)blockIdx.z * R * C;
  u16* dst = dst0 + (size_t)blockIdx.z * R * C;
  const int tid = threadIdx.x;
  const int r0 = blockIdx.y * 64, c0 = blockIdx.x * 64;
  const int ty = tid >> 4, tx = tid & 15;
#pragma unroll
  for (int i = 0; i < 4; i++){
    int row = ty + i * 16;
    f32x4 v = *(const f32x4*)&src[(size_t)(r0 + row) * C + c0 + tx * 4];
#pragma unroll
    for (int j = 0; j < 4; j++) tl[row][tx * 4 + j] = v[j];
  }
  __syncthreads();
#pragma unroll
  for (int i = 0; i < 4; i++){
    int drow = ty + i * 16;
    u16x4 o;
#pragma unroll
    for (int j = 0; j < 4; j++) o[j] = f2b(tl[tx * 4 + j][drow]);
    *(u16x4*)&dst[(size_t)(c0 + drow) * R + r0 + tx * 4] = o;
  }
}

// ---------------- fp32 -> bf16 hi/lo split ----------------
__global__ __launch_bounds__(256) void split_k(const float* __restrict__ src,
                                               u16* __restrict__ dh, u16* __restrict__ dl, int n4){
  int i = blockIdx.x * 256 + threadIdx.x;
  if (i < n4){
    f32x4 v = *(const f32x4*)&src[(size_t)i * 4];
    u16x4 oh, ol;
#pragma unroll
    for (int j = 0; j < 4; j++){ u16 hh, ll; tsplit(v[j], hh, ll); oh[j] = hh; ol[j] = ll; }
    *(u16x4*)&dh[(size_t)i * 4] = oh;
    *(u16x4*)&dl[(size_t)i * 4] = ol;
  }
}

// ---------------- layernorm (fp32 in, bf16 hi [+lo] out) ----------------
__global__ __launch_bounds__(256) void ln_k(const float* __restrict__ x, const float* __restrict__ g,
                                            const float* __restrict__ b,
                                            u16* __restrict__ outH, u16* __restrict__ outL){
  __shared__ float red[8];
  const int row = blockIdx.x, tid = threadIdx.x, l = tid & 63, wave = tid >> 6;
  f32x4 v = *(const f32x4*)&x[(size_t)row * DM + tid * 4];
  float s = v[0] + v[1] + v[2] + v[3];
  float sq = v[0]*v[0] + v[1]*v[1] + v[2]*v[2] + v[3]*v[3];
#pragma unroll
  for (int m = 1; m < 64; m <<= 1){ s += __shfl_xor(s, m); sq += __shfl_xor(sq, m); }
  if (l == 0){ red[wave] = s; red[4 + wave] = sq; }
  __syncthreads();
  float tot = red[0] + red[1] + red[2] + red[3];
  float totq = red[4] + red[5] + red[6] + red[7];
  float mean = tot * (1.0f / DM);
  float var = totq * (1.0f / DM) - mean * mean;
  float rstd = rsqrtf(var + 1e-5f);
  f32x4 gg = *(const f32x4*)&g[tid * 4];
  f32x4 bb = *(const f32x4*)&b[tid * 4];
  u16x4 oh, ol;
#pragma unroll
  for (int j = 0; j < 4; j++){
    float y = (v[j] - mean) * rstd * gg[j] + bb[j];
    u16 hh, ll; tsplit(y, hh, ll); oh[j] = hh; ol[j] = ll;
  }
  *(u16x4*)&outH[(size_t)row * DM + tid * 4] = oh;
  if (outL) *(u16x4*)&outL[(size_t)row * DM + tid * 4] = ol;
}

// ---------------- fused QKV projection v2: 512 thr, BM=128 BN=128, BK=64, m-pinned XCD ----------
// Unchanged from 807.4us baseline (clean A/B vs moe pipeline change).
struct QKVArgs {
  const u16* ah[3]; const u16* al[3]; const float* bias[3];
};

__global__ __launch_bounds__(512) void gemm_qkv3_k(
    QKVArgs args, const u16* __restrict__ Bhp, const u16* __restrict__ Blp,
    u16* __restrict__ QH, u16* __restrict__ QL,
    u16* __restrict__ KH, u16* __restrict__ KL,
    u16* __restrict__ VTH, u16* __restrict__ VTL)
{
  constexpr int K = DM;
  __shared__ alignas(16) u16 LAh[2][128 * 32], LAl[2][128 * 32];
  __shared__ alignas(16) u16 LBh[2][128 * 32], LBl[2][128 * 32];
  const int tid = threadIdx.x, l = tid & 63, wave = tid >> 6;
  const int id = blockIdx.x;
  const int mlo = id & 7, nb = (id >> 3) & 7, mhi = (id >> 6) & 3, seg = id >> 8;
  const int m0 = (mlo + 8 * mhi) * 128, n0 = nb * 128;
  const int r0 = tid >> 2, seg8 = (tid & 3) * 8;       // 512 threads cover [128][32]
  const u16* gAh = args.ah[seg] + (size_t)(m0 + r0) * K + seg8;
  const u16* gAl = args.al[seg] + (size_t)(m0 + r0) * K + seg8;
  const u16* gBh = Bhp + (size_t)(seg * 1024 + n0 + r0) * K + seg8;
  const u16* gBl = Blp + (size_t)(seg * 1024 + n0 + r0) * K + seg8;
  u16* wAh0 = &LAh[0][wave * 512]; u16* wAh1 = &LAh[1][wave * 512];
  u16* wAl0 = &LAl[0][wave * 512]; u16* wAl1 = &LAl[1][wave * 512];
  u16* wBh0 = &LBh[0][wave * 512]; u16* wBh1 = &LBh[1][wave * 512];
  u16* wBl0 = &LBl[0][wave * 512]; u16* wBl1 = &LBl[1][wave * 512];
  f32x4 acc[4][2];
#pragma unroll
  for (int i = 0; i < 4; i++)
#pragma unroll
    for (int j = 0; j < 2; j++) acc[i][j] = f32x4{0.f, 0.f, 0.f, 0.f};
  const int wm = (wave >> 2) * 64, wn = (wave & 3) * 32;
  for (int kt = 0; kt < K; kt += 64){
    __syncthreads();
    glds16(gAh + kt, wAh0); glds16(gAh + kt + 32, wAh1);
    glds16(gAl + kt, wAl0); glds16(gAl + kt + 32, wAl1);
    glds16(gBh + kt, wBh0); glds16(gBh + kt + 32, wBh1);
    glds16(gBl + kt, wBl0); glds16(gBl + kt + 32, wBl1);
    __syncthreads();
#pragma unroll
    for (int p = 0; p < 2; p++){
      s16x8 afh[4], afl[4], bfh[2], bfl[2];
#pragma unroll
      for (int i = 0; i < 4; i++){
        int ar = (wm + i * 16 + (l & 15)) * 32 + (l >> 4) * 8;
        afh[i] = *(const s16x8*)&LAh[p][ar];
        afl[i] = *(const s16x8*)&LAl[p][ar];
      }
#pragma unroll
      for (int j = 0; j < 2; j++){
        int br = (wn + j * 16 + (l & 15)) * 32 + (l >> 4) * 8;
        bfh[j] = *(const s16x8*)&LBh[p][br];
        bfl[j] = *(const s16x8*)&LBl[p][br];
      }
#pragma unroll
      for (int i = 0; i < 4; i++)
#pragma unroll
        for (int j = 0; j < 2; j++)
          acc[i][j] = mfma3(afh[i], afl[i], bfh[j], bfl[j], acc[i][j]);
    }
  }
  const float* bp = args.bias[seg];
  u16* DH = (seg == 0) ? QH : KH;
  u16* DL = (seg == 0) ? QL : KL;
#pragma unroll
  for (int i = 0; i < 4; i++)
#pragma unroll
    for (int r = 0; r < 4; r++){
      int row = m0 + wm + i * 16 + (l >> 4) * 4 + r;
#pragma unroll
      for (int j = 0; j < 2; j++){
        int col = n0 + wn + j * 16 + (l & 15);
        float v = acc[i][j][r] + bp[col];
        u16 hv, lv; tsplit(v, hv, lv);
        if (seg == 2){
          int bb = row >> 10, tq = row & 1023, hh = col >> 6, dd = col & 63;
          size_t vi = ((size_t)((bb << 4) + hh) * 64 + dd) * 1024 + tq;
          VTH[vi] = hv; VTL[vi] = lv;
        } else {
          size_t idx = (size_t)row * 1024 + col;
          DH[idx] = hv; DL[idx] = lv;
        }
      }
    }
}

// ---------------- O-projection GEMM, BM=64 x BN=64 (grid 16x64) ----------------
__global__ __launch_bounds__(256) void gemm_o64_k(
    const u16* __restrict__ Ahp, const u16* __restrict__ Alp,
    const u16* __restrict__ Bhp, const u16* __restrict__ Blp,
    const float* __restrict__ bias, const float* __restrict__ res,
    float* __restrict__ Cf)
{
  constexpr int K = DM;
  __shared__ alignas(16) u16 LAh[64 * 32], LAl[64 * 32];
  __shared__ alignas(16) u16 LBh[64 * 32], LBl[64 * 32];
  const int tid = threadIdx.x, l = tid & 63, wave = tid >> 6;
  const int m0 = blockIdx.y * 64, n0 = blockIdx.x * 64;
  const int rA = tid >> 2, seg8 = (tid & 3) * 8;
  const u16* gAh = Ahp + (size_t)(m0 + rA) * K + seg8;
  const u16* gAl = Alp + (size_t)(m0 + rA) * K + seg8;
  const u16* gBh = Bhp + (size_t)(n0 + rA) * K + seg8;
  const u16* gBl = Blp + (size_t)(n0 + rA) * K + seg8;
  u16* wAh = &LAh[wave * 512]; u16* wAl = &LAl[wave * 512];
  u16* wBh = &LBh[wave * 512]; u16* wBl = &LBl[wave * 512];
  f32x4 acc[2][2];
#pragma unroll
  for (int i = 0; i < 2; i++)
#pragma unroll
    for (int j = 0; j < 2; j++) acc[i][j] = f32x4{0.f, 0.f, 0.f, 0.f};
  const int wm = (wave >> 1) * 32, wn = (wave & 1) * 32;
  for (int kt = 0; kt < K; kt += 32){
    __syncthreads();
    glds16(gAh + kt, wAh);
    glds16(gAl + kt, wAl);
    glds16(gBh + kt, wBh);
    glds16(gBl + kt, wBl);
    __syncthreads();
    s16x8 afh[2], afl[2], bfh[2], bfl[2];
#pragma unroll
    for (int i = 0; i < 2; i++){
      int ar = (wm + i * 16 + (l & 15)) * 32 + (l >> 4) * 8;
      afh[i] = *(const s16x8*)&LAh[ar];
      afl[i] = *(const s16x8*)&LAl[ar];
    }
#pragma unroll
    for (int j = 0; j < 2; j++){
      int br = (wn + j * 16 + (l & 15)) * 32 + (l >> 4) * 8;
      bfh[j] = *(const s16x8*)&LBh[br];
      bfl[j] = *(const s16x8*)&LBl[br];
    }
#pragma unroll
    for (int i = 0; i < 2; i++)
#pragma unroll
      for (int j = 0; j < 2; j++)
        acc[i][j] = mfma3(afh[i], afl[i], bfh[j], bfl[j], acc[i][j]);
  }
#pragma unroll
  for (int i = 0; i < 2; i++)
#pragma unroll
    for (int r = 0; r < 4; r++){
      int row = m0 + wm + i * 16 + (l >> 4) * 4 + r;
#pragma unroll
      for (int j = 0; j < 2; j++){
        int col = n0 + wn + j * 16 + (l & 15);
        size_t idx = (size_t)row * 1024 + col;
        Cf[idx] = acc[i][j][r] + bias[col] + res[idx];
      }
    }
}

// ---------------- flash attention v5: LDS-staged K/V tiles (m97-style), split-K kseg=2 ----------------
template<bool CAUSAL>
__global__ __launch_bounds__(512) void attn5_k(
    const u16* __restrict__ Qh, const u16* __restrict__ Ql,
    const u16* __restrict__ Kh, const u16* __restrict__ Kl,
    const u16* __restrict__ Vth, const u16* __restrict__ Vtl,
    const int* __restrict__ mask,
    float* __restrict__ OP0, float* __restrict__ OP1,
    float* __restrict__ LS0, float* __restrict__ LS1,
    int Tq, int Tk)
{
  constexpr float CS = 0.125f * 1.4426950408889634f;  // 1/sqrt(64) * log2(e)
  __shared__ alignas(16) u16 KhiL[2048], KloL[2048];   // [32 key][64 d] u16, chunk-swizzled
  __shared__ alignas(16) u16 VhiL[2048], VloL[2048];   // [64 d][32 kt] u16, chunk-swizzled
  __shared__ alignas(16) u16 Plh[8][640], Pll[8][640]; // per-wave P tile, stride 40
  const int tid = threadIdx.x, l = tid & 63, wave = tid >> 6;
  const int id = blockIdx.x;
  const int bh = ((id >> 3) & 7) * 8 + (id & 7);
  const int b = bh >> 4, h = bh & 15;
  const int qt = (id >> 6) & 7, ks = id >> 9;
  const int q0 = qt * 128;
  float* __restrict__ OP = ks ? OP1 : OP0;
  float* __restrict__ LS = ks ? LS1 : LS0;
  // block-uniform key range
  const int ktBeg = ks * 512;
  int lim = CAUSAL ? (q0 + 128) : Tk;
  if (lim > Tk) lim = Tk;
  int ktEnd = (ks + 1) * 512;
  if (ktEnd > lim) ktEnd = lim;

  // Q fragments (per-wave 16 q-rows)
  const int qr = q0 + wave * 16 + (l & 15);
  s16x8 qah[2], qal[2];
#pragma unroll
  for (int kb = 0; kb < 2; kb++){
    size_t base = (size_t)(b * Tq + qr) * DM + h * 64 + kb * 32 + (l >> 4) * 8;
    qah[kb] = *(const s16x8*)(Qh + base);
    qal[kb] = *(const s16x8*)(Ql + base);
  }

  // staging assignments: waves 0-3 hi, 4-7 lo; within half: 256 lanes cover the tile
  const int sHalf = wave >> 2;          // 0=hi, 1=lo (wave-uniform)
  const int sw = wave & 3;
  const int iS = sw * 64 + l;           // 0..255 within half
  const int keyS = iS >> 3, cKS = iS & 7;
  const u16* gK = (sHalf ? Kl : Kh)
      + (size_t)(b * Tk + ktBeg + keyS) * DM + h * 64 + ((cKS ^ (keyS & 7)) * 8);
  u16* dK = (sHalf ? KloL : KhiL) + sw * 512;
  const int dS = iS >> 2, cVS = iS & 3;
  const size_t vgbase = (size_t)bh * 64 * 1024;
  const u16* gV = (sHalf ? Vtl : Vth)
      + vgbase + (size_t)dS * 1024 + ktBeg + ((cVS ^ ((dS >> 1) & 3)) * 8);
  u16* dV = (sHalf ? VloL : VhiL) + sw * 512;

  float lsum[4] = {0.f, 0.f, 0.f, 0.f};
  f32x4 oacc[4];
#pragma unroll
  for (int nb = 0; nb < 4; nb++) oacc[nb] = f32x4{0.f, 0.f, 0.f, 0.f};
  const int qgr = q0 + wave * 16 + (l >> 4) * 4;

  for (int kt = ktBeg; kt < ktEnd; kt += 32){
    __syncthreads();                      // prior tile's LDS reads drained
    glds16(gK, dK); gK += (size_t)32 * DM;
    glds16(gV, dV); gV += 32;
    __syncthreads();                      // staging complete (vmcnt drained by compiler)

    // QK^T: two 16-key halves (short kf live range)
    f32x4 s[2];
#pragma unroll
    for (int n = 0; n < 2; n++){
      s[n] = f32x4{0.f, 0.f, 0.f, 0.f};
      const int key = n * 16 + (l & 15);
      const int sK = (key & 7);
#pragma unroll
      for (int kb = 0; kb < 2; kb++){
        const int cK = kb * 4 + (l >> 4);
        const int off = key * 64 + ((cK ^ sK) * 8);
        s16x8 kh = *(const s16x8*)&KhiL[off];
        s16x8 klo = *(const s16x8*)&KloL[off];
        s[n] = __builtin_amdgcn_mfma_f32_16x16x32_bf16(qah[kb], kh, s[n], 0, 0, 0);
        s[n] = __builtin_amdgcn_mfma_f32_16x16x32_bf16(qah[kb], klo, s[n], 0, 0, 0);
        s[n] = __builtin_amdgcn_mfma_f32_16x16x32_bf16(qal[kb], kh, s[n], 0, 0, 0);
      }
    }
    int key0 = kt + (l & 15), key1 = key0 + 16;
    int mv0 = 1, mv1 = 1;
    if (!CAUSAL && mask){ mv0 = mask[b * Tk + key0]; mv1 = mask[b * Tk + key1]; }
#pragma unroll
    for (int r = 0; r < 4; r++){
      float p0, p1;
      if (CAUSAL){
        int qg = qgr + r;
        p0 = (key0 <= qg) ? fexp2(s[0][r] * CS) : 0.f;
        p1 = (key1 <= qg) ? fexp2(s[1][r] * CS) : 0.f;
      } else {
        p0 = mv0 ? fexp2(s[0][r] * CS) : 0.f;
        p1 = mv1 ? fexp2(s[1][r] * CS) : 0.f;
      }
      lsum[r] += p0 + p1;
      int po = ((l >> 4) * 4 + r) * 40 + (l & 15);
      u16 h0, l0, h1, l1;
      tsplit(p0, h0, l0); tsplit(p1, h1, l1);
      Plh[wave][po] = h0;      Pll[wave][po] = l0;
      Plh[wave][po + 16] = h1; Pll[wave][po + 16] = l1;
    }
    s16x8 pah = *(const s16x8*)&Plh[wave][(l & 15) * 40 + (l >> 4) * 8];
    s16x8 pal = *(const s16x8*)&Pll[wave][(l & 15) * 40 + (l >> 4) * 8];
    // PV: V^T fragments from LDS (swizzled)
#pragma unroll
    for (int nb = 0; nb < 4; nb++){
      const int d = nb * 16 + (l & 15);
      const int off = d * 32 + (((l >> 4) ^ ((d >> 1) & 3)) * 8);
      s16x8 vfh = *(const s16x8*)&VhiL[off];
      s16x8 vfl = *(const s16x8*)&VloL[off];
      oacc[nb] = mfma3(pah, pal, vfh, vfl, oacc[nb]);
    }
  }
#pragma unroll
  for (int r = 0; r < 4; r++){
    float s = lsum[r];
    s += __shfl_xor(s, 1); s += __shfl_xor(s, 2);
    s += __shfl_xor(s, 4); s += __shfl_xor(s, 8);
    int qg = qgr + r;
    if ((l & 15) == 0) LS[(size_t)bh * 1024 + qg] = s;
#pragma unroll
    for (int nb = 0; nb < 4; nb++)
      OP[(size_t)(b * Tq + qg) * DM + h * 64 + nb * 16 + (l & 15)] = oacc[nb][r];
  }
}

// ---------------- combine partials: O = (OP0+OP1)/(LS0+LS1) -> bf16 hi/lo ----------------
__global__ __launch_bounds__(256) void norm_k(
    const float* __restrict__ OP0, const float* __restrict__ OP1,
    const float* __restrict__ LS0, const float* __restrict__ LS1,
    u16* __restrict__ Oh, u16* __restrict__ Ol)
{
  const int t = blockIdx.x, c = threadIdx.x * 4;
  const int b = t >> 10, q = t & 1023, h = c >> 6;
  const size_t li = (size_t)(b * 16 + h) * 1024 + q;
  float inv = 1.0f / (LS0[li] + LS1[li]);
  f32x4 o0 = *(const f32x4*)&OP0[(size_t)t * DM + c];
  f32x4 o1 = *(const f32x4*)&OP1[(size_t)t * DM + c];
  u16x4 oh, ol;
#pragma unroll
  for (int j = 0; j < 4; j++){
    float v = (o0[j] + o1[j]) * inv;
    u16 hh, ll; tsplit(v, hh, ll); oh[j] = hh; ol[j] = ll;
  }
  *(u16x4*)&Oh[(size_t)t * DM + c] = oh;
  *(u16x4*)&Ol[(size_t)t * DM + c] = ol;
}

// ---------------- MoE gating: fp32, inline LN from H2 ----------------
__global__ __launch_bounds__(256) void moe_gate_k(const float* __restrict__ X,
    const float* __restrict__ g3, const float* __restrict__ b3,
    const float* __restrict__ wg, const float* __restrict__ bg,
    int* __restrict__ cnt, int* __restrict__ perm,
    int* __restrict__ toke, int* __restrict__ tokp, float* __restrict__ tokg)
{
  const int wave = threadIdx.x >> 6, l = threadIdx.x & 63;
  const int t = blockIdx.x * 4 + wave;
  float xv[16];
  float s = 0.f, sq = 0.f;
#pragma unroll
  for (int i = 0; i < 16; i++){
    xv[i] = X[(size_t)t * DM + l + i * 64];
    s += xv[i]; sq += xv[i] * xv[i];
  }
#pragma unroll
  for (int m = 1; m < 64; m <<= 1){ s += __shfl_xor(s, m); sq += __shfl_xor(sq, m); }
  float mean = s * (1.0f / DM);
  float var = sq * (1.0f / DM) - mean * mean;
  float rstd = rsqrtf(var + 1e-5f);
  float acc[8];
#pragma unroll
  for (int e = 0; e < 8; e++) acc[e] = 0.f;
#pragma unroll
  for (int i = 0; i < 16; i++){
    int k = l + i * 64;
    float xn = (xv[i] - mean) * rstd * g3[k] + b3[k];
    f32x4 wa = *(const f32x4*)&wg[k * 8];
    f32x4 wb = *(const f32x4*)&wg[k * 8 + 4];
#pragma unroll
    for (int j = 0; j < 4; j++){ acc[j] += xn * wa[j]; acc[4 + j] += xn * wb[j]; }
  }
#pragma unroll
  for (int e = 0; e < 8; e++)
#pragma unroll
    for (int m = 1; m < 64; m <<= 1) acc[e] += __shfl_xor(acc[e], m);
  if (l == 0){
    float lg[8];
#pragma unroll
    for (int e = 0; e < 8; e++) lg[e] = acc[e] + bg[e];
    float mx = lg[0];
#pragma unroll
    for (int e = 1; e < 8; e++) mx = fmaxf(mx, lg[e]);
    float ex[8]; float sum = 0.f;
#pragma unroll
    for (int e = 0; e < 8; e++){ ex[e] = expf(lg[e] - mx); sum += ex[e]; }
    int i0 = 0;
    for (int e = 1; e < 8; e++) if (ex[e] > ex[i0]) i0 = e;
    int i1 = (i0 == 0) ? 1 : 0;
    for (int e = 0; e < 8; e++) if (e != i0 && ex[e] > ex[i1]) i1 = e;
    float p0 = ex[i0] / sum, p1 = ex[i1] / sum;
    float gs = p0 + p1;
    int pos0 = atomicAdd(&cnt[i0], 1);
    int pos1 = atomicAdd(&cnt[i1], 1);
    perm[i0 * 4096 + pos0] = t;
    perm[i1 * 4096 + pos1] = t;
    toke[2 * t] = i0; toke[2 * t + 1] = i1;
    tokp[2 * t] = pos0; tokp[2 * t + 1] = pos1;
    tokg[2 * t] = p0 / gs; tokg[2 * t + 1] = p1 / gs;
  }
}

__global__ void offsets_k(const int* __restrict__ cnt, int* __restrict__ off){
  if (threadIdx.x == 0){
    int a = 0;
    for (int e = 0; e < 8; e++){ off[e] = a; a += cnt[e]; }
  }
}

// ---------------- MoE grouped GEMM 1 v5: BK=64 double-buffered counted-vmcnt pipeline ----------
// Per iter: issue stage(t+1) -> vmcnt(4) [t's loads done, t+1's stay in flight across barrier]
// -> s_barrier -> fence -> free interior (ds+48 MFMA) -> fence -> s_barrier.
// Same barrier count as the __syncthreads baseline; only the drain is removed.
__global__ __launch_bounds__(512) void gemm_moe1_k(
    const u16* __restrict__ X, const u16* __restrict__ W1t, const float* __restrict__ b1,
    const int* __restrict__ perm, const int* __restrict__ cnt, const int* __restrict__ off,
    u16* __restrict__ Hb)
{
  const int id = blockIdx.x;
  const int e = id & 7;
  const int rest = id >> 3;
  const int n0 = (rest & 31) * 128;       // FFD/128 = 32 n-tiles
  const int mt = rest >> 5;               // 0..31
  const int Ce = cnt[e];
  if (mt * 128 >= Ce) return;             // block-uniform (before any barrier)
  __shared__ alignas(16) u16 Asl[2][2][128 * 32];   // [buf][panel]
  __shared__ alignas(16) u16 Bsl[2][2][128 * 32];
  const int tid = threadIdx.x, l = tid & 63, wave = tid >> 6;
  const int r0 = tid >> 2, seg = (tid & 3) * 8;   // 512 threads cover [128][32]
  const int rl = mt * 128 + r0;
  const int g = perm[e * 4096 + (rl < Ce ? rl : Ce - 1)];
  const u16* gA = X + (size_t)g * DM + seg;
  const u16* gB = W1t + (size_t)e * FFD * DM + (size_t)(n0 + r0) * DM + seg;
  const int wo = wave * 512;
  f32x4 acc[4][2];
#pragma unroll
  for (int i = 0; i < 4; i++)
#pragma unroll
    for (int j = 0; j < 2; j++) acc[i][j] = f32x4{0.f,0.f,0.f,0.f};
  const int wm = (wave >> 2) * 64, wn = (wave & 3) * 32;
  // prologue: tile 0 -> buf 0
  glds16(gA,      &Asl[0][0][wo]); glds16(gA + 32, &Asl[0][1][wo]);
  glds16(gB,      &Bsl[0][0][wo]); glds16(gB + 32, &Bsl[0][1][wo]);
  constexpr int NT = DM / 64;             // 16 tiles
  for (int t = 0; t < NT; t++){
    const int cur = t & 1, nxt = cur ^ 1;
    if (t < NT - 1){
      const int kt = (t + 1) * 64;
      glds16(gA + kt,      &Asl[nxt][0][wo]); glds16(gA + kt + 32, &Asl[nxt][1][wo]);
      glds16(gB + kt,      &Bsl[nxt][0][wo]); glds16(gB + kt + 32, &Bsl[nxt][1][wo]);
      asm volatile("s_waitcnt vmcnt(4)" ::: "memory");   // tile t done; t+1 in flight
    } else {
      asm volatile("s_waitcnt vmcnt(0)" ::: "memory");
    }
    __builtin_amdgcn_s_barrier();          // tile t visible across waves
    __builtin_amdgcn_sched_barrier(0);     // no ds_read above
#pragma unroll
    for (int p = 0; p < 2; p++){
      s16x8 af[4], bfr[2];
#pragma unroll
      for (int i = 0; i < 4; i++)
        af[i]  = *(const s16x8*)&Asl[cur][p][(wm + i * 16 + (l & 15)) * 32 + (l >> 4) * 8];
#pragma unroll
      for (int j = 0; j < 2; j++)
        bfr[j] = *(const s16x8*)&Bsl[cur][p][(wn + j * 16 + (l & 15)) * 32 + (l >> 4) * 8];
#pragma unroll
      for (int i = 0; i < 4; i++)
#pragma unroll
        for (int j = 0; j < 2; j++)
          acc[i][j] = __builtin_amdgcn_mfma_f32_16x16x32_bf16(af[i], bfr[j], acc[i][j], 0, 0, 0);
    }
    __builtin_amdgcn_sched_barrier(0);     // no ds/MFMA below
    __builtin_amdgcn_s_barrier();          // reads of buf[cur] done before overwrite (iter t+1)
  }
  const int base = off[e];
#pragma unroll
  for (int i = 0; i < 4; i++)
#pragma unroll
    for (int r = 0; r < 4; r++){
      int rloc = mt * 128 + wm + i * 16 + (l >> 4) * 4 + r;
      if (rloc < Ce){
#pragma unroll
        for (int j = 0; j < 2; j++){
          int col = n0 + wn + j * 16 + (l & 15);
          float v = acc[i][j][r] + b1[e * FFD + col];
          v = fmaxf(v, 0.f);
          Hb[(size_t)(base + rloc) * FFD + col] = f2b(v);
        }
      }
    }
}

// ---------------- MoE grouped GEMM 2 v5: BK=64 double-buffered counted-vmcnt pipeline ----------
__global__ __launch_bounds__(512) void gemm_moe2_k(
    const u16* __restrict__ Hb, const u16* __restrict__ W2t,
    const int* __restrict__ cnt, const int* __restrict__ off, float* __restrict__ Y)
{
  const int id = blockIdx.x;
  const int e = id & 7;
  const int rest = id >> 3;
  const int n0 = (rest & 7) * 128;
  const int mt = rest >> 3;               // 0..31
  const int Ce = cnt[e];
  if (mt * 128 >= Ce) return;             // block-uniform
  __shared__ alignas(16) u16 Asl[2][2][128 * 32];
  __shared__ alignas(16) u16 Bsl[2][2][128 * 32];
  const int tid = threadIdx.x, l = tid & 63, wave = tid >> 6;
  const int r0 = tid >> 2, seg = (tid & 3) * 8;
  const int base = off[e];
  const int rl = mt * 128 + r0;
  const int ar = base + (rl < Ce ? rl : Ce - 1);
  const u16* gA = Hb + (size_t)ar * FFD + seg;
  const u16* gB = W2t + (size_t)e * DM * FFD + (size_t)(n0 + r0) * FFD + seg;
  const int wo = wave * 512;
  f32x4 acc[4][2];
#pragma unroll
  for (int i = 0; i < 4; i++)
#pragma unroll
    for (int j = 0; j < 2; j++) acc[i][j] = f32x4{0.f,0.f,0.f,0.f};
  const int wm = (wave >> 2) * 64, wn = (wave & 3) * 32;
  glds16(gA,      &Asl[0][0][wo]); glds16(gA + 32, &Asl[0][1][wo]);
  glds16(gB,      &Bsl[0][0][wo]); glds16(gB + 32, &Bsl[0][1][wo]);
  constexpr int NT = FFD / 64;            // 64 tiles
  for (int t = 0; t < NT; t++){
    const int cur = t & 1, nxt = cur ^ 1;
    if (t < NT - 1){
      const int kt = (t + 1) * 64;
      glds16(gA + kt,      &Asl[nxt][0][wo]); glds16(gA + kt + 32, &Asl[nxt][1][wo]);
      glds16(gB + kt,      &Bsl[nxt][0][wo]); glds16(gB + kt + 32, &Bsl[nxt][1][wo]);
      asm volatile("s_waitcnt vmcnt(4)" ::: "memory");
    } else {
      asm volatile("s_waitcnt vmcnt(0)" ::: "memory");
    }
    __builtin_amdgcn_s_barrier();
    __builtin_amdgcn_sched_barrier(0);
#pragma unroll
    for (int p = 0; p < 2; p++){
      s16x8 af[4], bfr[2];
#pragma unroll
      for (int i = 0; i < 4; i++)
        af[i]  = *(const s16x8*)&Asl[cur][p][(wm + i * 16 + (l & 15)) * 32 + (l >> 4) * 8];
#pragma unroll
      for (int j = 0; j < 2; j++)
        bfr[j] = *(const s16x8*)&Bsl[cur][p][(wn + j * 16 + (l & 15)) * 32 + (l >> 4) * 8];
#pragma unroll
      for (int i = 0; i < 4; i++)
#pragma unroll
        for (int j = 0; j < 2; j++)
          acc[i][j] = __builtin_amdgcn_mfma_f32_16x16x32_bf16(af[i], bfr[j], acc[i][j], 0, 0, 0);
    }
    __builtin_amdgcn_sched_barrier(0);
    __builtin_amdgcn_s_barrier();
  }
#pragma unroll
  for (int i = 0; i < 4; i++)
#pragma unroll
    for (int r = 0; r < 4; r++){
      int rloc = mt * 128 + wm + i * 16 + (l >> 4) * 4 + r;
      if (rloc < Ce){
#pragma unroll
        for (int j = 0; j < 2; j++){
          int col = n0 + wn + j * 16 + (l & 15);
          Y[(size_t)(base + rloc) * DM + col] = acc[i][j][r];
        }
      }
    }
}

__global__ __launch_bounds__(256) void combine_k(const float* __restrict__ h2,
    const float* __restrict__ Y,
    const int* __restrict__ toke, const int* __restrict__ tokp, const float* __restrict__ tokg,
    const int* __restrict__ off, const float* __restrict__ b2, float* __restrict__ out)
{
  const int t = blockIdx.x;
  const int c = threadIdx.x * 4;
  int e0 = toke[2 * t], e1 = toke[2 * t + 1];
  size_t r0 = (size_t)off[e0] + tokp[2 * t];
  size_t r1 = (size_t)off[e1] + tokp[2 * t + 1];
  float g0 = tokg[2 * t], g1 = tokg[2 * t + 1];
  f32x4 a  = *(const f32x4*)&h2[(size_t)t * DM + c];
  f32x4 y0 = *(const f32x4*)&Y[r0 * DM + c];
  f32x4 y1 = *(const f32x4*)&Y[r1 * DM + c];
  f32x4 v0 = *(const f32x4*)&b2[(size_t)e0 * DM + c];
  f32x4 v1 = *(const f32x4*)&b2[(size_t)e1 * DM + c];
  f32x4 o = a + (y0 + v0) * g0 + (y1 + v1) * g1;
  *(f32x4*)&out[(size_t)t * DM + c] = o;
}

// ---------------- host ----------------
extern "C" void kernel_launch(void* const* d_in, const int* in_sizes, int n_in,
                              void* d_out, int out_size, void* d_ws, size_t ws_size,
                              hipStream_t stream) {
  const float* x    = (const float*)d_in[0];
  const float* enc  = (const float*)d_in[1];
  const int* smask  = (const int*)d_in[2];
  const float* ln1g = (const float*)d_in[4]; const float* ln1b = (const float*)d_in[5];
  const float* ln2g = (const float*)d_in[6]; const float* ln2b = (const float*)d_in[7];
  const float* ln3g = (const float*)d_in[8]; const float* ln3b = (const float*)d_in[9];
  const float* wq1 = (const float*)d_in[10]; const float* bq1 = (const float*)d_in[11];
  const float* wk1 = (const float*)d_in[12]; const float* bk1 = (const float*)d_in[13];
  const float* wv1 = (const float*)d_in[14]; const float* bv1 = (const float*)d_in[15];
  const float* wo1 = (const float*)d_in[16]; const float* bo1 = (const float*)d_in[17];
  const float* wq2 = (const float*)d_in[18]; const float* bq2 = (const float*)d_in[19];
  const float* wk2 = (const float*)d_in[20]; const float* bk2 = (const float*)d_in[21];
  const float* wv2 = (const float*)d_in[22]; const float* bv2 = (const float*)d_in[23];
  const float* wo2 = (const float*)d_in[24]; const float* bo2 = (const float*)d_in[25];
  const float* wg  = (const float*)d_in[26]; const float* bg  = (const float*)d_in[27];
  const float* w1  = (const float*)d_in[28]; const float* b1  = (const float*)d_in[29];
  const float* w2  = (const float*)d_in[30]; const float* b2  = (const float*)d_in[31];

  const size_t MB = 1024ull * 1024ull;
  char* ws = (char*)d_ws;
  size_t o = 0;
  auto alloc = [&](size_t bytes) -> void* {
    void* p = ws + o;
    o += (bytes + 255) & ~(size_t)255;
    return p;
  };
  // persistent
  float* H1  = (float*)alloc(16 * MB);
  float* H2  = (float*)alloc(16 * MB);
  u16*  NBF  = (u16*) alloc(8 * MB);
  int* CNT  = (int*)alloc(256);
  int* OFF  = (int*)alloc(256);
  int* PERM = (int*)alloc((size_t)8 * 4096 * 4);
  int* TOKE = (int*)alloc((size_t)NTOK * 2 * 4);
  int* TOKP = (int*)alloc((size_t)NTOK * 2 * 4);
  float* TOKG = (float*)alloc((size_t)NTOK * 2 * 4);
  // phase-overlapped region (224 MiB): phase1 = attention, phase2 = MoE
  char* R = (char*)alloc(224 * MB);
  u16* WTH = (u16*)(R);               // 16 MB (8 attn weights hi, transposed)
  u16* WTL = (u16*)(R + 16 * MB);     // 16 MB (lo)
  u16* NH  = (u16*)(R + 32 * MB);     // 8 MB
  u16* NL  = (u16*)(R + 40 * MB);
  u16* EH  = (u16*)(R + 48 * MB);
  u16* EL  = (u16*)(R + 56 * MB);
  u16* QH  = (u16*)(R + 64 * MB);
  u16* QL  = (u16*)(R + 72 * MB);
  u16* KH  = (u16*)(R + 80 * MB);
  u16* KL  = (u16*)(R + 88 * MB);
  u16* VTH = (u16*)(R + 96 * MB);     // V^T [B*H][64][1024]
  u16* VTL = (u16*)(R + 104 * MB);
  u16* OH  = (u16*)(R + 112 * MB);
  u16* OL  = (u16*)(R + 120 * MB);    // ends 128 MB
  float* OP0 = (float*)(R + 128 * MB); // 16 MB unnormalized O partial (kseg 0)
  float* OP1 = (float*)(R + 144 * MB); // 16 MB (kseg 1)
  float* LS0 = (float*)(R + 160 * MB); // 256 KB row-sum partials
  float* LS1 = (float*)(R + 161 * MB); // 256 KB
  u16* W1T = (u16*)(R);               // 64 MB (phase 2 overlays phase 1)
  u16* W2T = (u16*)(R + 64 * MB);     // 64 MB
  u16* HB  = (u16*)(R + 128 * MB);    // 64 MB
  float* YB = (float*)(R + 192 * MB); // 32 MB fp32 Y

  // weights -> bf16 hi/lo transposed; enc -> hi/lo split
  Ptr8 p8; p8.p[0]=wq1; p8.p[1]=wk1; p8.p[2]=wv1; p8.p[3]=wo1;
           p8.p[4]=wq2; p8.p[5]=wk2; p8.p[6]=wv2; p8.p[7]=wo2;
  trans8_k<<<dim3(16,16,8), 256, 0, stream>>>(p8, WTH, WTL);
  split_k<<<dim3(4096), 256, 0, stream>>>(enc, EH, EL, NTOK * DM / 4);

  const size_t W = (size_t)1024 * 1024;
  // ---- self-attention ----
  ln_k<<<dim3(NTOK), 256, 0, stream>>>(x, ln1g, ln1b, NH, NL);
  {
    QKVArgs a;
    a.ah[0]=NH; a.ah[1]=NH; a.ah[2]=NH;
    a.al[0]=NL; a.al[1]=NL; a.al[2]=NL;
    a.bias[0]=bq1; a.bias[1]=bk1; a.bias[2]=bv1;
    gemm_qkv3_k<<<dim3(768), 512, 0, stream>>>(a, WTH + 0*W, WTL + 0*W,
                                               QH, QL, KH, KL, VTH, VTL);
  }
  attn5_k<true><<<dim3(1024), 512, 0, stream>>>(QH, QL, KH, KL, VTH, VTL, nullptr,
                                                OP0, OP1, LS0, LS1, TT, TT);
  norm_k<<<dim3(NTOK), 256, 0, stream>>>(OP0, OP1, LS0, LS1, OH, OL);
  gemm_o64_k<<<dim3(16,64), 256, 0, stream>>>(OH, OL, WTH + 3*W, WTL + 3*W, bo1, x, H1);

  // ---- cross-attention ----
  ln_k<<<dim3(NTOK), 256, 0, stream>>>(H1, ln2g, ln2b, NH, NL);
  {
    QKVArgs a;
    a.ah[0]=NH; a.ah[1]=EH; a.ah[2]=EH;
    a.al[0]=NL; a.al[1]=EL; a.al[2]=EL;
    a.bias[0]=bq2; a.bias[1]=bk2; a.bias[2]=bv2;
    gemm_qkv3_k<<<dim3(768), 512, 0, stream>>>(a, WTH + 4*W, WTL + 4*W,
                                               QH, QL, KH, KL, VTH, VTL);
  }
  attn5_k<false><<<dim3(1024), 512, 0, stream>>>(QH, QL, KH, KL, VTH, VTL, smask,
                                                 OP0, OP1, LS0, LS1, TT, TT);
  norm_k<<<dim3(NTOK), 256, 0, stream>>>(OP0, OP1, LS0, LS1, OH, OL);
  gemm_o64_k<<<dim3(16,64), 256, 0, stream>>>(OH, OL, WTH + 7*W, WTL + 7*W, bo2, H1, H2);

  // ---- MoE (phase 2 overlays phase-1 buffers) ----
  transb_k<<<dim3(64,16,8), 256, 0, stream>>>(w1, W1T, 1024, 4096);
  transb_k<<<dim3(16,64,8), 256, 0, stream>>>(w2, W2T, 4096, 1024);
  ln_k<<<dim3(NTOK), 256, 0, stream>>>(H2, ln3g, ln3b, NBF, nullptr);
  hipMemsetAsync(CNT, 0, 8 * sizeof(int), stream);
  moe_gate_k<<<dim3(1024), 256, 0, stream>>>(H2, ln3g, ln3b, wg, bg, CNT, PERM, TOKE, TOKP, TOKG);
  offsets_k<<<dim3(1), 64, 0, stream>>>(CNT, OFF);
  gemm_moe1_k<<<dim3(8192), 512, 0, stream>>>(NBF, W1T, b1, PERM, CNT, OFF, HB);
  gemm_moe2_k<<<dim3(2048), 512, 0, stream>>>(HB, W2T, CNT, OFF, YB);
  combine_k<<<dim3(NTOK), 256, 0, stream>>>(H2, YB, TOKE, TOKP, TOKG, OFF, b2, (float*)d_out);
}

// Round 19
// 803.403 us; speedup vs baseline: 1.0776x; 1.0776x over previous
//
#include <hip/hip_runtime.h>

typedef unsigned short u16;
typedef float f32x4 __attribute__((ext_vector_type(4)));
typedef short s16x8 __attribute__((ext_vector_type(8)));
typedef u16   u16x4 __attribute__((ext_vector_type(4)));

#define DEV static __device__ __forceinline__

DEV u16 f2b(float f){
  unsigned u = __builtin_bit_cast(unsigned, f);
  u += 0x7fffu + ((u >> 16) & 1u);
  return (u16)(u >> 16);
}
DEV float b2f(u16 h){ unsigned u = ((unsigned)h) << 16; return __builtin_bit_cast(float, u); }
// truncation split: hi = trunc-to-bf16(v); lo = trunc(v - hi). 2-term error ~2^-16 rel.
DEV void tsplit(float v, u16& hv, u16& lv){
  unsigned u = __builtin_bit_cast(unsigned, v);
  hv = (u16)(u >> 16);
  float rest = v - __builtin_bit_cast(float, u & 0xffff0000u);
  lv = (u16)(__builtin_bit_cast(unsigned, rest) >> 16);
}
DEV float fexp2(float x){ float r; asm("v_exp_f32 %0, %1" : "=v"(r) : "v"(x)); return r; }

// async global->LDS, 16B per lane. LDS dest wave-uniform base; HW adds lane*16.
DEV void glds16(const u16* g, u16* l){
  __builtin_amdgcn_global_load_lds(
      (const __attribute__((address_space(1))) void*)g,
      (__attribute__((address_space(3))) void*)l, 16, 0, 0);
}

DEV f32x4 mfma3(s16x8 ah, s16x8 al, s16x8 bh, s16x8 bl, f32x4 c){
  c = __builtin_amdgcn_mfma_f32_16x16x32_bf16(ah, bh, c, 0, 0, 0);
  c = __builtin_amdgcn_mfma_f32_16x16x32_bf16(ah, bl, c, 0, 0, 0);
  c = __builtin_amdgcn_mfma_f32_16x16x32_bf16(al, bh, c, 0, 0, 0);
  return c;
}

constexpr int TT = 1024, DM = 1024, NE = 8, FFD = 4096;
constexpr int NTOK = 4096;

// ---------------- transpose fp32 [1024][1024] -> bf16 hi/lo [C][R] ----------------
struct Ptr8 { const float* p[8]; };

__global__ __launch_bounds__(256) void trans8_k(Ptr8 srcs, u16* __restrict__ dh, u16* __restrict__ dl){
  __shared__ float tl[64][65];
  const float* src = srcs.p[blockIdx.z];
  u16* dsth = dh + (size_t)blockIdx.z * 1024 * 1024;
  u16* dstl = dl + (size_t)blockIdx.z * 1024 * 1024;
  const int tid = threadIdx.x;
  const int r0 = blockIdx.y * 64, c0 = blockIdx.x * 64;
  const int ty = tid >> 4, tx = tid & 15;
#pragma unroll
  for (int i = 0; i < 4; i++){
    int row = ty + i * 16;
    f32x4 v = *(const f32x4*)&src[(size_t)(r0 + row) * 1024 + c0 + tx * 4];
#pragma unroll
    for (int j = 0; j < 4; j++) tl[row][tx * 4 + j] = v[j];
  }
  __syncthreads();
#pragma unroll
  for (int i = 0; i < 4; i++){
    int drow = ty + i * 16;
    u16x4 oh, ol;
#pragma unroll
    for (int j = 0; j < 4; j++){
      float v = tl[tx * 4 + j][drow];
      u16 hh, ll; tsplit(v, hh, ll);
      oh[j] = hh; ol[j] = ll;
    }
    *(u16x4*)&dsth[(size_t)(c0 + drow) * 1024 + r0 + tx * 4] = oh;
    *(u16x4*)&dstl[(size_t)(c0 + drow) * 1024 + r0 + tx * 4] = ol;
  }
}

// single-bf16 transpose for MoE weights
__global__ __launch_bounds__(256) void transb_k(const float* __restrict__ src0, u16* __restrict__ dst0, int R, int C){
  __shared__ float tl[64][65];
  const float* src = src0 + (size_t)blockIdx.z * R * C;
  u16* dst = dst0 + (size_t)blockIdx.z * R * C;
  const int tid = threadIdx.x;
  const int r0 = blockIdx.y * 64, c0 = blockIdx.x * 64;
  const int ty = tid >> 4, tx = tid & 15;
#pragma unroll
  for (int i = 0; i < 4; i++){
    int row = ty + i * 16;
    f32x4 v = *(const f32x4*)&src[(size_t)(r0 + row) * C + c0 + tx * 4];
#pragma unroll
    for (int j = 0; j < 4; j++) tl[row][tx * 4 + j] = v[j];
  }
  __syncthreads();
#pragma unroll
  for (int i = 0; i < 4; i++){
    int drow = ty + i * 16;
    u16x4 o;
#pragma unroll
    for (int j = 0; j < 4; j++) o[j] = f2b(tl[tx * 4 + j][drow]);
    *(u16x4*)&dst[(size_t)(c0 + drow) * R + r0 + tx * 4] = o;
  }
}

// ---------------- fp32 -> bf16 hi/lo split ----------------
__global__ __launch_bounds__(256) void split_k(const float* __restrict__ src,
                                               u16* __restrict__ dh, u16* __restrict__ dl, int n4){
  int i = blockIdx.x * 256 + threadIdx.x;
  if (i < n4){
    f32x4 v = *(const f32x4*)&src[(size_t)i * 4];
    u16x4 oh, ol;
#pragma unroll
    for (int j = 0; j < 4; j++){ u16 hh, ll; tsplit(v[j], hh, ll); oh[j] = hh; ol[j] = ll; }
    *(u16x4*)&dh[(size_t)i * 4] = oh;
    *(u16x4*)&dl[(size_t)i * 4] = ol;
  }
}

// ---------------- layernorm (fp32 in, bf16 hi [+lo] out) ----------------
__global__ __launch_bounds__(256) void ln_k(const float* __restrict__ x, const float* __restrict__ g,
                                            const float* __restrict__ b,
                                            u16* __restrict__ outH, u16* __restrict__ outL){
  __shared__ float red[8];
  const int row = blockIdx.x, tid = threadIdx.x, l = tid & 63, wave = tid >> 6;
  f32x4 v = *(const f32x4*)&x[(size_t)row * DM + tid * 4];
  float s = v[0] + v[1] + v[2] + v[3];
  float sq = v[0]*v[0] + v[1]*v[1] + v[2]*v[2] + v[3]*v[3];
#pragma unroll
  for (int m = 1; m < 64; m <<= 1){ s += __shfl_xor(s, m); sq += __shfl_xor(sq, m); }
  if (l == 0){ red[wave] = s; red[4 + wave] = sq; }
  __syncthreads();
  float tot = red[0] + red[1] + red[2] + red[3];
  float totq = red[4] + red[5] + red[6] + red[7];
  float mean = tot * (1.0f / DM);
  float var = totq * (1.0f / DM) - mean * mean;
  float rstd = rsqrtf(var + 1e-5f);
  f32x4 gg = *(const f32x4*)&g[tid * 4];
  f32x4 bb = *(const f32x4*)&b[tid * 4];
  u16x4 oh, ol;
#pragma unroll
  for (int j = 0; j < 4; j++){
    float y = (v[j] - mean) * rstd * gg[j] + bb[j];
    u16 hh, ll; tsplit(y, hh, ll); oh[j] = hh; ol[j] = ll;
  }
  *(u16x4*)&outH[(size_t)row * DM + tid * 4] = oh;
  if (outL) *(u16x4*)&outL[(size_t)row * DM + tid * 4] = ol;
}

// ---------------- fused QKV projection v2: 512 thr, BM=128 BN=128, BK=64, m-pinned XCD ----------
// Best-known config (807.4 us baseline). R15/R16/R18 falsified source-level pipelining on
// this structure (m131-m141 / m196 / occupancy loss at 64KB dbuf).
struct QKVArgs {
  const u16* ah[3]; const u16* al[3]; const float* bias[3];
};

__global__ __launch_bounds__(512) void gemm_qkv3_k(
    QKVArgs args, const u16* __restrict__ Bhp, const u16* __restrict__ Blp,
    u16* __restrict__ QH, u16* __restrict__ QL,
    u16* __restrict__ KH, u16* __restrict__ KL,
    u16* __restrict__ VTH, u16* __restrict__ VTL)
{
  constexpr int K = DM;
  __shared__ alignas(16) u16 LAh[2][128 * 32], LAl[2][128 * 32];
  __shared__ alignas(16) u16 LBh[2][128 * 32], LBl[2][128 * 32];
  const int tid = threadIdx.x, l = tid & 63, wave = tid >> 6;
  const int id = blockIdx.x;
  const int mlo = id & 7, nb = (id >> 3) & 7, mhi = (id >> 6) & 3, seg = id >> 8;
  const int m0 = (mlo + 8 * mhi) * 128, n0 = nb * 128;
  const int r0 = tid >> 2, seg8 = (tid & 3) * 8;       // 512 threads cover [128][32]
  const u16* gAh = args.ah[seg] + (size_t)(m0 + r0) * K + seg8;
  const u16* gAl = args.al[seg] + (size_t)(m0 + r0) * K + seg8;
  const u16* gBh = Bhp + (size_t)(seg * 1024 + n0 + r0) * K + seg8;
  const u16* gBl = Blp + (size_t)(seg * 1024 + n0 + r0) * K + seg8;
  u16* wAh0 = &LAh[0][wave * 512]; u16* wAh1 = &LAh[1][wave * 512];
  u16* wAl0 = &LAl[0][wave * 512]; u16* wAl1 = &LAl[1][wave * 512];
  u16* wBh0 = &LBh[0][wave * 512]; u16* wBh1 = &LBh[1][wave * 512];
  u16* wBl0 = &LBl[0][wave * 512]; u16* wBl1 = &LBl[1][wave * 512];
  f32x4 acc[4][2];
#pragma unroll
  for (int i = 0; i < 4; i++)
#pragma unroll
    for (int j = 0; j < 2; j++) acc[i][j] = f32x4{0.f, 0.f, 0.f, 0.f};
  const int wm = (wave >> 2) * 64, wn = (wave & 3) * 32;
  for (int kt = 0; kt < K; kt += 64){
    __syncthreads();
    glds16(gAh + kt, wAh0); glds16(gAh + kt + 32, wAh1);
    glds16(gAl + kt, wAl0); glds16(gAl + kt + 32, wAl1);
    glds16(gBh + kt, wBh0); glds16(gBh + kt + 32, wBh1);
    glds16(gBl + kt, wBl0); glds16(gBl + kt + 32, wBl1);
    __syncthreads();
#pragma unroll
    for (int p = 0; p < 2; p++){
      s16x8 afh[4], afl[4], bfh[2], bfl[2];
#pragma unroll
      for (int i = 0; i < 4; i++){
        int ar = (wm + i * 16 + (l & 15)) * 32 + (l >> 4) * 8;
        afh[i] = *(const s16x8*)&LAh[p][ar];
        afl[i] = *(const s16x8*)&LAl[p][ar];
      }
#pragma unroll
      for (int j = 0; j < 2; j++){
        int br = (wn + j * 16 + (l & 15)) * 32 + (l >> 4) * 8;
        bfh[j] = *(const s16x8*)&LBh[p][br];
        bfl[j] = *(const s16x8*)&LBl[p][br];
      }
#pragma unroll
      for (int i = 0; i < 4; i++)
#pragma unroll
        for (int j = 0; j < 2; j++)
          acc[i][j] = mfma3(afh[i], afl[i], bfh[j], bfl[j], acc[i][j]);
    }
  }
  const float* bp = args.bias[seg];
  u16* DH = (seg == 0) ? QH : KH;
  u16* DL = (seg == 0) ? QL : KL;
#pragma unroll
  for (int i = 0; i < 4; i++)
#pragma unroll
    for (int r = 0; r < 4; r++){
      int row = m0 + wm + i * 16 + (l >> 4) * 4 + r;
#pragma unroll
      for (int j = 0; j < 2; j++){
        int col = n0 + wn + j * 16 + (l & 15);
        float v = acc[i][j][r] + bp[col];
        u16 hv, lv; tsplit(v, hv, lv);
        if (seg == 2){
          int bb = row >> 10, tq = row & 1023, hh = col >> 6, dd = col & 63;
          size_t vi = ((size_t)((bb << 4) + hh) * 64 + dd) * 1024 + tq;
          VTH[vi] = hv; VTL[vi] = lv;
        } else {
          size_t idx = (size_t)row * 1024 + col;
          DH[idx] = hv; DL[idx] = lv;
        }
      }
    }
}

// ---------------- O-projection GEMM, BM=64 x BN=64 (grid 16x64) ----------------
__global__ __launch_bounds__(256) void gemm_o64_k(
    const u16* __restrict__ Ahp, const u16* __restrict__ Alp,
    const u16* __restrict__ Bhp, const u16* __restrict__ Blp,
    const float* __restrict__ bias, const float* __restrict__ res,
    float* __restrict__ Cf)
{
  constexpr int K = DM;
  __shared__ alignas(16) u16 LAh[64 * 32], LAl[64 * 32];
  __shared__ alignas(16) u16 LBh[64 * 32], LBl[64 * 32];
  const int tid = threadIdx.x, l = tid & 63, wave = tid >> 6;
  const int m0 = blockIdx.y * 64, n0 = blockIdx.x * 64;
  const int rA = tid >> 2, seg8 = (tid & 3) * 8;
  const u16* gAh = Ahp + (size_t)(m0 + rA) * K + seg8;
  const u16* gAl = Alp + (size_t)(m0 + rA) * K + seg8;
  const u16* gBh = Bhp + (size_t)(n0 + rA) * K + seg8;
  const u16* gBl = Blp + (size_t)(n0 + rA) * K + seg8;
  u16* wAh = &LAh[wave * 512]; u16* wAl = &LAl[wave * 512];
  u16* wBh = &LBh[wave * 512]; u16* wBl = &LBl[wave * 512];
  f32x4 acc[2][2];
#pragma unroll
  for (int i = 0; i < 2; i++)
#pragma unroll
    for (int j = 0; j < 2; j++) acc[i][j] = f32x4{0.f, 0.f, 0.f, 0.f};
  const int wm = (wave >> 1) * 32, wn = (wave & 1) * 32;
  for (int kt = 0; kt < K; kt += 32){
    __syncthreads();
    glds16(gAh + kt, wAh);
    glds16(gAl + kt, wAl);
    glds16(gBh + kt, wBh);
    glds16(gBl + kt, wBl);
    __syncthreads();
    s16x8 afh[2], afl[2], bfh[2], bfl[2];
#pragma unroll
    for (int i = 0; i < 2; i++){
      int ar = (wm + i * 16 + (l & 15)) * 32 + (l >> 4) * 8;
      afh[i] = *(const s16x8*)&LAh[ar];
      afl[i] = *(const s16x8*)&LAl[ar];
    }
#pragma unroll
    for (int j = 0; j < 2; j++){
      int br = (wn + j * 16 + (l & 15)) * 32 + (l >> 4) * 8;
      bfh[j] = *(const s16x8*)&LBh[br];
      bfl[j] = *(const s16x8*)&LBl[br];
    }
#pragma unroll
    for (int i = 0; i < 2; i++)
#pragma unroll
      for (int j = 0; j < 2; j++)
        acc[i][j] = mfma3(afh[i], afl[i], bfh[j], bfl[j], acc[i][j]);
  }
#pragma unroll
  for (int i = 0; i < 2; i++)
#pragma unroll
    for (int r = 0; r < 4; r++){
      int row = m0 + wm + i * 16 + (l >> 4) * 4 + r;
#pragma unroll
      for (int j = 0; j < 2; j++){
        int col = n0 + wn + j * 16 + (l & 15);
        size_t idx = (size_t)row * 1024 + col;
        Cf[idx] = acc[i][j][r] + bias[col] + res[idx];
      }
    }
}

// ---------------- flash attention v5: LDS-staged K/V tiles (m97-style), split-K kseg=2 ----------------
template<bool CAUSAL>
__global__ __launch_bounds__(512) void attn5_k(
    const u16* __restrict__ Qh, const u16* __restrict__ Ql,
    const u16* __restrict__ Kh, const u16* __restrict__ Kl,
    const u16* __restrict__ Vth, const u16* __restrict__ Vtl,
    const int* __restrict__ mask,
    float* __restrict__ OP0, float* __restrict__ OP1,
    float* __restrict__ LS0, float* __restrict__ LS1,
    int Tq, int Tk)
{
  constexpr float CS = 0.125f * 1.4426950408889634f;  // 1/sqrt(64) * log2(e)
  __shared__ alignas(16) u16 KhiL[2048], KloL[2048];   // [32 key][64 d] u16, chunk-swizzled
  __shared__ alignas(16) u16 VhiL[2048], VloL[2048];   // [64 d][32 kt] u16, chunk-swizzled
  __shared__ alignas(16) u16 Plh[8][640], Pll[8][640]; // per-wave P tile, stride 40
  const int tid = threadIdx.x, l = tid & 63, wave = tid >> 6;
  const int id = blockIdx.x;
  const int bh = ((id >> 3) & 7) * 8 + (id & 7);
  const int b = bh >> 4, h = bh & 15;
  const int qt = (id >> 6) & 7, ks = id >> 9;
  const int q0 = qt * 128;
  float* __restrict__ OP = ks ? OP1 : OP0;
  float* __restrict__ LS = ks ? LS1 : LS0;
  // block-uniform key range
  const int ktBeg = ks * 512;
  int lim = CAUSAL ? (q0 + 128) : Tk;
  if (lim > Tk) lim = Tk;
  int ktEnd = (ks + 1) * 512;
  if (ktEnd > lim) ktEnd = lim;

  // Q fragments (per-wave 16 q-rows)
  const int qr = q0 + wave * 16 + (l & 15);
  s16x8 qah[2], qal[2];
#pragma unroll
  for (int kb = 0; kb < 2; kb++){
    size_t base = (size_t)(b * Tq + qr) * DM + h * 64 + kb * 32 + (l >> 4) * 8;
    qah[kb] = *(const s16x8*)(Qh + base);
    qal[kb] = *(const s16x8*)(Ql + base);
  }

  // staging assignments: waves 0-3 hi, 4-7 lo; within half: 256 lanes cover the tile
  const int sHalf = wave >> 2;          // 0=hi, 1=lo (wave-uniform)
  const int sw = wave & 3;
  const int iS = sw * 64 + l;           // 0..255 within half
  const int keyS = iS >> 3, cKS = iS & 7;
  const u16* gK = (sHalf ? Kl : Kh)
      + (size_t)(b * Tk + ktBeg + keyS) * DM + h * 64 + ((cKS ^ (keyS & 7)) * 8);
  u16* dK = (sHalf ? KloL : KhiL) + sw * 512;
  const int dS = iS >> 2, cVS = iS & 3;
  const size_t vgbase = (size_t)bh * 64 * 1024;
  const u16* gV = (sHalf ? Vtl : Vth)
      + vgbase + (size_t)dS * 1024 + ktBeg + ((cVS ^ ((dS >> 1) & 3)) * 8);
  u16* dV = (sHalf ? VloL : VhiL) + sw * 512;

  float lsum[4] = {0.f, 0.f, 0.f, 0.f};
  f32x4 oacc[4];
#pragma unroll
  for (int nb = 0; nb < 4; nb++) oacc[nb] = f32x4{0.f, 0.f, 0.f, 0.f};
  const int qgr = q0 + wave * 16 + (l >> 4) * 4;

  for (int kt = ktBeg; kt < ktEnd; kt += 32){
    __syncthreads();                      // prior tile's LDS reads drained
    glds16(gK, dK); gK += (size_t)32 * DM;
    glds16(gV, dV); gV += 32;
    __syncthreads();                      // staging complete (vmcnt drained by compiler)

    // QK^T: two 16-key halves (short kf live range)
    f32x4 s[2];
#pragma unroll
    for (int n = 0; n < 2; n++){
      s[n] = f32x4{0.f, 0.f, 0.f, 0.f};
      const int key = n * 16 + (l & 15);
      const int sK = (key & 7);
#pragma unroll
      for (int kb = 0; kb < 2; kb++){
        const int cK = kb * 4 + (l >> 4);
        const int off = key * 64 + ((cK ^ sK) * 8);
        s16x8 kh = *(const s16x8*)&KhiL[off];
        s16x8 klo = *(const s16x8*)&KloL[off];
        s[n] = __builtin_amdgcn_mfma_f32_16x16x32_bf16(qah[kb], kh, s[n], 0, 0, 0);
        s[n] = __builtin_amdgcn_mfma_f32_16x16x32_bf16(qah[kb], klo, s[n], 0, 0, 0);
        s[n] = __builtin_amdgcn_mfma_f32_16x16x32_bf16(qal[kb], kh, s[n], 0, 0, 0);
      }
    }
    int key0 = kt + (l & 15), key1 = key0 + 16;
    int mv0 = 1, mv1 = 1;
    if (!CAUSAL && mask){ mv0 = mask[b * Tk + key0]; mv1 = mask[b * Tk + key1]; }
#pragma unroll
    for (int r = 0; r < 4; r++){
      float p0, p1;
      if (CAUSAL){
        int qg = qgr + r;
        p0 = (key0 <= qg) ? fexp2(s[0][r] * CS) : 0.f;
        p1 = (key1 <= qg) ? fexp2(s[1][r] * CS) : 0.f;
      } else {
        p0 = mv0 ? fexp2(s[0][r] * CS) : 0.f;
        p1 = mv1 ? fexp2(s[1][r] * CS) : 0.f;
      }
      lsum[r] += p0 + p1;
      int po = ((l >> 4) * 4 + r) * 40 + (l & 15);
      u16 h0, l0, h1, l1;
      tsplit(p0, h0, l0); tsplit(p1, h1, l1);
      Plh[wave][po] = h0;      Pll[wave][po] = l0;
      Plh[wave][po + 16] = h1; Pll[wave][po + 16] = l1;
    }
    s16x8 pah = *(const s16x8*)&Plh[wave][(l & 15) * 40 + (l >> 4) * 8];
    s16x8 pal = *(const s16x8*)&Pll[wave][(l & 15) * 40 + (l >> 4) * 8];
    // PV: V^T fragments from LDS (swizzled)
#pragma unroll
    for (int nb = 0; nb < 4; nb++){
      const int d = nb * 16 + (l & 15);
      const int off = d * 32 + (((l >> 4) ^ ((d >> 1) & 3)) * 8);
      s16x8 vfh = *(const s16x8*)&VhiL[off];
      s16x8 vfl = *(const s16x8*)&VloL[off];
      oacc[nb] = mfma3(pah, pal, vfh, vfl, oacc[nb]);
    }
  }
#pragma unroll
  for (int r = 0; r < 4; r++){
    float s = lsum[r];
    s += __shfl_xor(s, 1); s += __shfl_xor(s, 2);
    s += __shfl_xor(s, 4); s += __shfl_xor(s, 8);
    int qg = qgr + r;
    if ((l & 15) == 0) LS[(size_t)bh * 1024 + qg] = s;
#pragma unroll
    for (int nb = 0; nb < 4; nb++)
      OP[(size_t)(b * Tq + qg) * DM + h * 64 + nb * 16 + (l & 15)] = oacc[nb][r];
  }
}

// ---------------- combine partials: O = (OP0+OP1)/(LS0+LS1) -> bf16 hi/lo ----------------
__global__ __launch_bounds__(256) void norm_k(
    const float* __restrict__ OP0, const float* __restrict__ OP1,
    const float* __restrict__ LS0, const float* __restrict__ LS1,
    u16* __restrict__ Oh, u16* __restrict__ Ol)
{
  const int t = blockIdx.x, c = threadIdx.x * 4;
  const int b = t >> 10, q = t & 1023, h = c >> 6;
  const size_t li = (size_t)(b * 16 + h) * 1024 + q;
  float inv = 1.0f / (LS0[li] + LS1[li]);
  f32x4 o0 = *(const f32x4*)&OP0[(size_t)t * DM + c];
  f32x4 o1 = *(const f32x4*)&OP1[(size_t)t * DM + c];
  u16x4 oh, ol;
#pragma unroll
  for (int j = 0; j < 4; j++){
    float v = (o0[j] + o1[j]) * inv;
    u16 hh, ll; tsplit(v, hh, ll); oh[j] = hh; ol[j] = ll;
  }
  *(u16x4*)&Oh[(size_t)t * DM + c] = oh;
  *(u16x4*)&Ol[(size_t)t * DM + c] = ol;
}

// ---------------- MoE gating: fp32, inline LN from H2 ----------------
__global__ __launch_bounds__(256) void moe_gate_k(const float* __restrict__ X,
    const float* __restrict__ g3, const float* __restrict__ b3,
    const float* __restrict__ wg, const float* __restrict__ bg,
    int* __restrict__ cnt, int* __restrict__ perm,
    int* __restrict__ toke, int* __restrict__ tokp, float* __restrict__ tokg)
{
  const int wave = threadIdx.x >> 6, l = threadIdx.x & 63;
  const int t = blockIdx.x * 4 + wave;
  float xv[16];
  float s = 0.f, sq = 0.f;
#pragma unroll
  for (int i = 0; i < 16; i++){
    xv[i] = X[(size_t)t * DM + l + i * 64];
    s += xv[i]; sq += xv[i] * xv[i];
  }
#pragma unroll
  for (int m = 1; m < 64; m <<= 1){ s += __shfl_xor(s, m); sq += __shfl_xor(sq, m); }
  float mean = s * (1.0f / DM);
  float var = sq * (1.0f / DM) - mean * mean;
  float rstd = rsqrtf(var + 1e-5f);
  float acc[8];
#pragma unroll
  for (int e = 0; e < 8; e++) acc[e] = 0.f;
#pragma unroll
  for (int i = 0; i < 16; i++){
    int k = l + i * 64;
    float xn = (xv[i] - mean) * rstd * g3[k] + b3[k];
    f32x4 wa = *(const f32x4*)&wg[k * 8];
    f32x4 wb = *(const f32x4*)&wg[k * 8 + 4];
#pragma unroll
    for (int j = 0; j < 4; j++){ acc[j] += xn * wa[j]; acc[4 + j] += xn * wb[j]; }
  }
#pragma unroll
  for (int e = 0; e < 8; e++)
#pragma unroll
    for (int m = 1; m < 64; m <<= 1) acc[e] += __shfl_xor(acc[e], m);
  if (l == 0){
    float lg[8];
#pragma unroll
    for (int e = 0; e < 8; e++) lg[e] = acc[e] + bg[e];
    float mx = lg[0];
#pragma unroll
    for (int e = 1; e < 8; e++) mx = fmaxf(mx, lg[e]);
    float ex[8]; float sum = 0.f;
#pragma unroll
    for (int e = 0; e < 8; e++){ ex[e] = expf(lg[e] - mx); sum += ex[e]; }
    int i0 = 0;
    for (int e = 1; e < 8; e++) if (ex[e] > ex[i0]) i0 = e;
    int i1 = (i0 == 0) ? 1 : 0;
    for (int e = 0; e < 8; e++) if (e != i0 && ex[e] > ex[i1]) i1 = e;
    float p0 = ex[i0] / sum, p1 = ex[i1] / sum;
    float gs = p0 + p1;
    int pos0 = atomicAdd(&cnt[i0], 1);
    int pos1 = atomicAdd(&cnt[i1], 1);
    perm[i0 * 4096 + pos0] = t;
    perm[i1 * 4096 + pos1] = t;
    toke[2 * t] = i0; toke[2 * t + 1] = i1;
    tokp[2 * t] = pos0; tokp[2 * t + 1] = pos1;
    tokg[2 * t] = p0 / gs; tokg[2 * t + 1] = p1 / gs;
  }
}

__global__ void offsets_k(const int* __restrict__ cnt, int* __restrict__ off){
  if (threadIdx.x == 0){
    int a = 0;
    for (int e = 0; e < 8; e++){ off[e] = a; a += cnt[e]; }
  }
}

// ---------------- MoE grouped GEMM 1 v2: 512 thr, BM=128 BN=128, BK=64, e-pinned XCD ----------
__global__ __launch_bounds__(512) void gemm_moe1_k(
    const u16* __restrict__ X, const u16* __restrict__ W1t, const float* __restrict__ b1,
    const int* __restrict__ perm, const int* __restrict__ cnt, const int* __restrict__ off,
    u16* __restrict__ Hb)
{
  const int id = blockIdx.x;
  const int e = id & 7;
  const int rest = id >> 3;
  const int n0 = (rest & 31) * 128;       // FFD/128 = 32 n-tiles
  const int mt = rest >> 5;               // 0..31
  const int Ce = cnt[e];
  if (mt * 128 >= Ce) return;
  __shared__ alignas(16) u16 Asl[2][128 * 32];
  __shared__ alignas(16) u16 Bsl[2][128 * 32];
  const int tid = threadIdx.x, l = tid & 63, wave = tid >> 6;
  const int r0 = tid >> 2, seg = (tid & 3) * 8;   // 512 threads cover [128][32]
  const int rl = mt * 128 + r0;
  const int g = perm[e * 4096 + (rl < Ce ? rl : Ce - 1)];
  const u16* gA = X + (size_t)g * DM + seg;
  const u16* gB = W1t + (size_t)e * FFD * DM + (size_t)(n0 + r0) * DM + seg;
  u16* wA0 = &Asl[0][wave * 512]; u16* wA1 = &Asl[1][wave * 512];
  u16* wB0 = &Bsl[0][wave * 512]; u16* wB1 = &Bsl[1][wave * 512];
  f32x4 acc[4][2];
#pragma unroll
  for (int i = 0; i < 4; i++)
#pragma unroll
    for (int j = 0; j < 2; j++) acc[i][j] = f32x4{0.f,0.f,0.f,0.f};
  const int wm = (wave >> 2) * 64, wn = (wave & 3) * 32;
  for (int kt = 0; kt < DM; kt += 64){
    __syncthreads();
    glds16(gA + kt, wA0);
    glds16(gA + kt + 32, wA1);
    glds16(gB + kt, wB0);
    glds16(gB + kt + 32, wB1);
    __syncthreads();
#pragma unroll
    for (int p = 0; p < 2; p++){
      s16x8 af[4], bfr[2];
#pragma unroll
      for (int i = 0; i < 4; i++)
        af[i]  = *(const s16x8*)&Asl[p][(wm + i * 16 + (l & 15)) * 32 + (l >> 4) * 8];
#pragma unroll
      for (int j = 0; j < 2; j++)
        bfr[j] = *(const s16x8*)&Bsl[p][(wn + j * 16 + (l & 15)) * 32 + (l >> 4) * 8];
#pragma unroll
      for (int i = 0; i < 4; i++)
#pragma unroll
        for (int j = 0; j < 2; j++)
          acc[i][j] = __builtin_amdgcn_mfma_f32_16x16x32_bf16(af[i], bfr[j], acc[i][j], 0, 0, 0);
    }
  }
  const int base = off[e];
#pragma unroll
  for (int i = 0; i < 4; i++)
#pragma unroll
    for (int r = 0; r < 4; r++){
      int rloc = mt * 128 + wm + i * 16 + (l >> 4) * 4 + r;
      if (rloc < Ce){
#pragma unroll
        for (int j = 0; j < 2; j++){
          int col = n0 + wn + j * 16 + (l & 15);
          float v = acc[i][j][r] + b1[e * FFD + col];
          v = fmaxf(v, 0.f);
          Hb[(size_t)(base + rloc) * FFD + col] = f2b(v);
        }
      }
    }
}

// ---------------- MoE grouped GEMM 2: 512 thr, BM=128 BN=128, BK=64, e-pinned XCD ----------
__global__ __launch_bounds__(512) void gemm_moe2_k(
    const u16* __restrict__ Hb, const u16* __restrict__ W2t,
    const int* __restrict__ cnt, const int* __restrict__ off, float* __restrict__ Y)
{
  const int id = blockIdx.x;
  const int e = id & 7;
  const int rest = id >> 3;
  const int n0 = (rest & 7) * 128;
  const int mt = rest >> 3;               // 0..31
  const int Ce = cnt[e];
  if (mt * 128 >= Ce) return;
  __shared__ alignas(16) u16 Asl[2][128 * 32];
  __shared__ alignas(16) u16 Bsl[2][128 * 32];
  const int tid = threadIdx.x, l = tid & 63, wave = tid >> 6;
  const int r0 = tid >> 2, seg = (tid & 3) * 8;   // r0 0..127 (512 threads)
  const int base = off[e];
  const int rl = mt * 128 + r0;
  const int ar = base + (rl < Ce ? rl : Ce - 1);
  const u16* gA = Hb + (size_t)ar * FFD + seg;
  const u16* gB = W2t + (size_t)e * DM * FFD + (size_t)(n0 + r0) * FFD + seg;
  u16* wA0 = &Asl[0][wave * 512]; u16* wA1 = &Asl[1][wave * 512];
  u16* wB0 = &Bsl[0][wave * 512]; u16* wB1 = &Bsl[1][wave * 512];
  f32x4 acc[4][2];
#pragma unroll
  for (int i = 0; i < 4; i++)
#pragma unroll
    for (int j = 0; j < 2; j++) acc[i][j] = f32x4{0.f,0.f,0.f,0.f};
  const int wm = (wave >> 2) * 64, wn = (wave & 3) * 32;
  for (int kt = 0; kt < FFD; kt += 64){
    __syncthreads();
    glds16(gA + kt, wA0);
    glds16(gA + kt + 32, wA1);
    glds16(gB + kt, wB0);
    glds16(gB + kt + 32, wB1);
    __syncthreads();
#pragma unroll
    for (int p = 0; p < 2; p++){
      s16x8 af[4], bfr[2];
#pragma unroll
      for (int i = 0; i < 4; i++)
        af[i]  = *(const s16x8*)&Asl[p][(wm + i * 16 + (l & 15)) * 32 + (l >> 4) * 8];
#pragma unroll
      for (int j = 0; j < 2; j++)
        bfr[j] = *(const s16x8*)&Bsl[p][(wn + j * 16 + (l & 15)) * 32 + (l >> 4) * 8];
#pragma unroll
      for (int i = 0; i < 4; i++)
#pragma unroll
        for (int j = 0; j < 2; j++)
          acc[i][j] = __builtin_amdgcn_mfma_f32_16x16x32_bf16(af[i], bfr[j], acc[i][j], 0, 0, 0);
    }
  }
#pragma unroll
  for (int i = 0; i < 4; i++)
#pragma unroll
    for (int r = 0; r < 4; r++){
      int rloc = mt * 128 + wm + i * 16 + (l >> 4) * 4 + r;
      if (rloc < Ce){
#pragma unroll
        for (int j = 0; j < 2; j++){
          int col = n0 + wn + j * 16 + (l & 15);
          Y[(size_t)(base + rloc) * DM + col] = acc[i][j][r];
        }
      }
    }
}

__global__ __launch_bounds__(256) void combine_k(const float* __restrict__ h2,
    const float* __restrict__ Y,
    const int* __restrict__ toke, const int* __restrict__ tokp, const float* __restrict__ tokg,
    const int* __restrict__ off, const float* __restrict__ b2, float* __restrict__ out)
{
  const int t = blockIdx.x;
  const int c = threadIdx.x * 4;
  int e0 = toke[2 * t], e1 = toke[2 * t + 1];
  size_t r0 = (size_t)off[e0] + tokp[2 * t];
  size_t r1 = (size_t)off[e1] + tokp[2 * t + 1];
  float g0 = tokg[2 * t], g1 = tokg[2 * t + 1];
  f32x4 a  = *(const f32x4*)&h2[(size_t)t * DM + c];
  f32x4 y0 = *(const f32x4*)&Y[r0 * DM + c];
  f32x4 y1 = *(const f32x4*)&Y[r1 * DM + c];
  f32x4 v0 = *(const f32x4*)&b2[(size_t)e0 * DM + c];
  f32x4 v1 = *(const f32x4*)&b2[(size_t)e1 * DM + c];
  f32x4 o = a + (y0 + v0) * g0 + (y1 + v1) * g1;
  *(f32x4*)&out[(size_t)t * DM + c] = o;
}

// ---------------- host ----------------
extern "C" void kernel_launch(void* const* d_in, const int* in_sizes, int n_in,
                              void* d_out, int out_size, void* d_ws, size_t ws_size,
                              hipStream_t stream) {
  const float* x    = (const float*)d_in[0];
  const float* enc  = (const float*)d_in[1];
  const int* smask  = (const int*)d_in[2];
  const float* ln1g = (const float*)d_in[4]; const float* ln1b = (const float*)d_in[5];
  const float* ln2g = (const float*)d_in[6]; const float* ln2b = (const float*)d_in[7];
  const float* ln3g = (const float*)d_in[8]; const float* ln3b = (const float*)d_in[9];
  const float* wq1 = (const float*)d_in[10]; const float* bq1 = (const float*)d_in[11];
  const float* wk1 = (const float*)d_in[12]; const float* bk1 = (const float*)d_in[13];
  const float* wv1 = (const float*)d_in[14]; const float* bv1 = (const float*)d_in[15];
  const float* wo1 = (const float*)d_in[16]; const float* bo1 = (const float*)d_in[17];
  const float* wq2 = (const float*)d_in[18]; const float* bq2 = (const float*)d_in[19];
  const float* wk2 = (const float*)d_in[20]; const float* bk2 = (const float*)d_in[21];
  const float* wv2 = (const float*)d_in[22]; const float* bv2 = (const float*)d_in[23];
  const float* wo2 = (const float*)d_in[24]; const float* bo2 = (const float*)d_in[25];
  const float* wg  = (const float*)d_in[26]; const float* bg  = (const float*)d_in[27];
  const float* w1  = (const float*)d_in[28]; const float* b1  = (const float*)d_in[29];
  const float* w2  = (const float*)d_in[30]; const float* b2  = (const float*)d_in[31];

  const size_t MB = 1024ull * 1024ull;
  char* ws = (char*)d_ws;
  size_t o = 0;
  auto alloc = [&](size_t bytes) -> void* {
    void* p = ws + o;
    o += (bytes + 255) & ~(size_t)255;
    return p;
  };
  // persistent
  float* H1  = (float*)alloc(16 * MB);
  float* H2  = (float*)alloc(16 * MB);
  u16*  NBF  = (u16*) alloc(8 * MB);
  int* CNT  = (int*)alloc(256);
  int* OFF  = (int*)alloc(256);
  int* PERM = (int*)alloc((size_t)8 * 4096 * 4);
  int* TOKE = (int*)alloc((size_t)NTOK * 2 * 4);
  int* TOKP = (int*)alloc((size_t)NTOK * 2 * 4);
  float* TOKG = (float*)alloc((size_t)NTOK * 2 * 4);
  // phase-overlapped region (224 MiB): phase1 = attention, phase2 = MoE
  char* R = (char*)alloc(224 * MB);
  u16* WTH = (u16*)(R);               // 16 MB (8 attn weights hi, transposed)
  u16* WTL = (u16*)(R + 16 * MB);     // 16 MB (lo)
  u16* NH  = (u16*)(R + 32 * MB);     // 8 MB
  u16* NL  = (u16*)(R + 40 * MB);
  u16* EH  = (u16*)(R + 48 * MB);
  u16* EL  = (u16*)(R + 56 * MB);
  u16* QH  = (u16*)(R + 64 * MB);
  u16* QL  = (u16*)(R + 72 * MB);
  u16* KH  = (u16*)(R + 80 * MB);
  u16* KL  = (u16*)(R + 88 * MB);
  u16* VTH = (u16*)(R + 96 * MB);     // V^T [B*H][64][1024]
  u16* VTL = (u16*)(R + 104 * MB);
  u16* OH  = (u16*)(R + 112 * MB);
  u16* OL  = (u16*)(R + 120 * MB);    // ends 128 MB
  float* OP0 = (float*)(R + 128 * MB); // 16 MB unnormalized O partial (kseg 0)
  float* OP1 = (float*)(R + 144 * MB); // 16 MB (kseg 1)
  float* LS0 = (float*)(R + 160 * MB); // 256 KB row-sum partials
  float* LS1 = (float*)(R + 161 * MB); // 256 KB
  u16* W1T = (u16*)(R);               // 64 MB (phase 2 overlays phase 1)
  u16* W2T = (u16*)(R + 64 * MB);     // 64 MB
  u16* HB  = (u16*)(R + 128 * MB);    // 64 MB
  float* YB = (float*)(R + 192 * MB); // 32 MB fp32 Y

  // weights -> bf16 hi/lo transposed; enc -> hi/lo split
  Ptr8 p8; p8.p[0]=wq1; p8.p[1]=wk1; p8.p[2]=wv1; p8.p[3]=wo1;
           p8.p[4]=wq2; p8.p[5]=wk2; p8.p[6]=wv2; p8.p[7]=wo2;
  trans8_k<<<dim3(16,16,8), 256, 0, stream>>>(p8, WTH, WTL);
  split_k<<<dim3(4096), 256, 0, stream>>>(enc, EH, EL, NTOK * DM / 4);

  const size_t W = (size_t)1024 * 1024;
  // ---- self-attention ----
  ln_k<<<dim3(NTOK), 256, 0, stream>>>(x, ln1g, ln1b, NH, NL);
  {
    QKVArgs a;
    a.ah[0]=NH; a.ah[1]=NH; a.ah[2]=NH;
    a.al[0]=NL; a.al[1]=NL; a.al[2]=NL;
    a.bias[0]=bq1; a.bias[1]=bk1; a.bias[2]=bv1;
    gemm_qkv3_k<<<dim3(768), 512, 0, stream>>>(a, WTH + 0*W, WTL + 0*W,
                                               QH, QL, KH, KL, VTH, VTL);
  }
  attn5_k<true><<<dim3(1024), 512, 0, stream>>>(QH, QL, KH, KL, VTH, VTL, nullptr,
                                                OP0, OP1, LS0, LS1, TT, TT);
  norm_k<<<dim3(NTOK), 256, 0, stream>>>(OP0, OP1, LS0, LS1, OH, OL);
  gemm_o64_k<<<dim3(16,64), 256, 0, stream>>>(OH, OL, WTH + 3*W, WTL + 3*W, bo1, x, H1);

  // ---- cross-attention ----
  ln_k<<<dim3(NTOK), 256, 0, stream>>>(H1, ln2g, ln2b, NH, NL);
  {
    QKVArgs a;
    a.ah[0]=NH; a.ah[1]=EH; a.ah[2]=EH;
    a.al[0]=NL; a.al[1]=EL; a.al[2]=EL;
    a.bias[0]=bq2; a.bias[1]=bk2; a.bias[2]=bv2;
    gemm_qkv3_k<<<dim3(768), 512, 0, stream>>>(a, WTH + 4*W, WTL + 4*W,
                                               QH, QL, KH, KL, VTH, VTL);
  }
  attn5_k<false><<<dim3(1024), 512, 0, stream>>>(QH, QL, KH, KL, VTH, VTL, smask,
                                                 OP0, OP1, LS0, LS1, TT, TT);
  norm_k<<<dim3(NTOK), 256, 0, stream>>>(OP0, OP1, LS0, LS1, OH, OL);
  gemm_o64_k<<<dim3(16,64), 256, 0, stream>>>(OH, OL, WTH + 7*W, WTL + 7*W, bo2, H1, H2);

  // ---- MoE (phase 2 overlays phase-1 buffers) ----
  transb_k<<<dim3(64,16,8), 256, 0, stream>>>(w1, W1T, 1024, 4096);
  transb_k<<<dim3(16,64,8), 256, 0, stream>>>(w2, W2T, 4096, 1024);
  ln_k<<<dim3(NTOK), 256, 0, stream>>>(H2, ln3g, ln3b, NBF, nullptr);
  hipMemsetAsync(CNT, 0, 8 * sizeof(int), stream);
  moe_gate_k<<<dim3(1024), 256, 0, stream>>>(H2, ln3g, ln3b, wg, bg, CNT, PERM, TOKE, TOKP, TOKG);
  offsets_k<<<dim3(1), 64, 0, stream>>>(CNT, OFF);
  gemm_moe1_k<<<dim3(8192), 512, 0, stream>>>(NBF, W1T, b1, PERM, CNT, OFF, HB);
  gemm_moe2_k<<<dim3(2048), 512, 0, stream>>>(HB, W2T, CNT, OFF, YB);
  combine_k<<<dim3(NTOK), 256, 0, stream>>>(H2, YB, TOKE, TOKP, TOKG, OFF, b2, (float*)d_out);
}